// Round 1
// baseline (3059.309 us; speedup 1.0000x reference)
//
#include <hip/hip_runtime.h>
#include <hip/hip_bf16.h>
#include <stdint.h>

// ---------------------------------------------------------------------------
// MoDEChameleonMLP: gate/up/down GEMMs with LoRA (image) / rank-8 MoE (text)
// deltas folded into the GEMM K-dimension as augmented columns.
//   K1P = H + 40 (gate coeffs) + 40 (up coeffs) + 48 pad = 4224  (66*64)
//   K2P = I + 40 (down coeffs) + 88 pad               = 11136 (174*64)
// ---------------------------------------------------------------------------

#define H_DIM 4096
#define I_DIM 11008
#define N_TOK 4096
#define R_RANK 8
#define K1P 4224
#define K2P 11136

typedef __attribute__((ext_vector_type(8))) __bf16 bf16x8;
typedef __attribute__((ext_vector_type(4))) __bf16 bf16x4;
typedef __attribute__((ext_vector_type(4))) float  f32x4;

__device__ __forceinline__ void gload16(const void* g, const void* lds_wave_base) {
  // global -> LDS direct copy, 16B per lane. lds_wave_base must be wave-uniform;
  // HW adds lane*16.
  auto gp = (const __attribute__((address_space(1))) void*)(uintptr_t)g;
  auto lp = (__attribute__((address_space(3))) void*)(uintptr_t)lds_wave_base;
  __builtin_amdgcn_global_load_lds(gp, lp, 16, 0, 0);
}

// ---- mask dtype probe: 0/1 int32, 0/1.0f float32, or raw bytes (bool) ------
__device__ __forceinline__ void detect_mask(const void* mask, int t, int* okI, int* okF) {
  const unsigned int* mi = (const unsigned int*)mask;
  int bad_i = 0, bad_f = 0;
  for (int idx = t; idx < 1024; idx += 256) {   // first 4096 bytes: safe in all layouts
    unsigned v = mi[idx];
    bad_i |= !(v == 0u || v == 1u);
    bad_f |= !(v == 0u || v == 0x3f800000u);
  }
  if (bad_i) *okI = 0;
  if (bad_f) *okF = 0;
}

__device__ __forceinline__ bool read_mask(const void* mask, int n, int okI, int okF) {
  if (okI) return ((const int*)mask)[n] != 0;
  if (okF) return ((const float*)mask)[n] != 0.0f;
  return ((const unsigned char*)mask)[n] != 0;
}

// ---------------------------------------------------------------------------
// prep_w1: Wg_aug / Wu_aug rows: [bf16(W) | 2*vB | 2*tmB | zeros]
// ---------------------------------------------------------------------------
__global__ __launch_bounds__(256)
void prep_w1(const float* __restrict__ Wg, const float* __restrict__ Wu,
             const float* __restrict__ vBg, const float* __restrict__ tmBg,
             const float* __restrict__ vBu, const float* __restrict__ tmBu,
             __bf16* __restrict__ Wga, __bf16* __restrict__ Wua) {
  int i = blockIdx.x, t = threadIdx.x;
  const float4* g4 = (const float4*)(Wg + (size_t)i * H_DIM);
  const float4* u4 = (const float4*)(Wu + (size_t)i * H_DIM);
  __bf16* og = Wga + (size_t)i * K1P;
  __bf16* ou = Wua + (size_t)i * K1P;
  for (int c = t; c < H_DIM / 4; c += 256) {
    float4 v = g4[c];
    bf16x4 b = {(__bf16)v.x, (__bf16)v.y, (__bf16)v.z, (__bf16)v.w};
    *(bf16x4*)(og + c * 4) = b;
    v = u4[c];
    bf16x4 b2 = {(__bf16)v.x, (__bf16)v.y, (__bf16)v.z, (__bf16)v.w};
    *(bf16x4*)(ou + c * 4) = b2;
  }
  if (t < 128) {  // 40 gate-slots + 40 up-slots + 48 pad
    float gv = 0.f, uv = 0.f;
    if (t < 8) gv = 2.f * vBg[i * R_RANK + t];
    else if (t < 40) { int e = (t - 8) >> 3, r = (t - 8) & 7;
      gv = 2.f * tmBg[((size_t)e * I_DIM + i) * R_RANK + r]; }
    if (t >= 40 && t < 48) uv = 2.f * vBu[i * R_RANK + (t - 40)];
    else if (t >= 48 && t < 80) { int e = (t - 48) >> 3, r = (t - 48) & 7;
      uv = 2.f * tmBu[((size_t)e * I_DIM + i) * R_RANK + r]; }
    og[H_DIM + t] = (__bf16)gv;
    ou[H_DIM + t] = (__bf16)uv;
  }
}

// ---------------------------------------------------------------------------
// prep_wd: Wd_aug rows: [bf16(Wd) | 2*va_down_B | 2*tm_down_B | zeros]
// ---------------------------------------------------------------------------
__global__ __launch_bounds__(256)
void prep_wd(const float* __restrict__ Wd, const float* __restrict__ vBd,
             const float* __restrict__ tmBd, __bf16* __restrict__ Wda) {
  int o = blockIdx.x, t = threadIdx.x;
  const float4* w4 = (const float4*)(Wd + (size_t)o * I_DIM);
  __bf16* orow = Wda + (size_t)o * K2P;
  for (int c = t; c < I_DIM / 4; c += 256) {
    float4 v = w4[c];
    bf16x4 b = {(__bf16)v.x, (__bf16)v.y, (__bf16)v.z, (__bf16)v.w};
    *(bf16x4*)(orow + c * 4) = b;
  }
  if (t < 128) {
    float v = 0.f;
    if (t < 8) v = 2.f * vBd[o * R_RANK + t];
    else if (t < 40) { int e = (t - 8) >> 3, r = (t - 8) & 7;
      v = 2.f * tmBd[((size_t)e * H_DIM + o) * R_RANK + r]; }
    orow[I_DIM + t] = (__bf16)v;
  }
}

// ---------------------------------------------------------------------------
// prep_x: per token, bf16(x) + 88 skinny dots + router softmax -> coeff slots
// 4 tokens per block (amortizes adapter-row reads through L2).
// ---------------------------------------------------------------------------
__global__ __launch_bounds__(256)
void prep_x(const float* __restrict__ x, const void* __restrict__ mask,
            const float* __restrict__ vAg, const float* __restrict__ tmAg, const float* __restrict__ rg,
            const float* __restrict__ vAu, const float* __restrict__ tmAu, const float* __restrict__ ru,
            __bf16* __restrict__ Xaug) {
  __shared__ __align__(16) float sx[4][H_DIM];
  __shared__ float dots[4][88];
  __shared__ int okI, okF;
  int t = threadIdx.x, n0 = blockIdx.x * 4;
  if (t == 0) { okI = 1; okF = 1; }
  __syncthreads();
  detect_mask(mask, t, &okI, &okF);
  for (int tok = 0; tok < 4; ++tok) {
    const float4* xr = (const float4*)(x + (size_t)(n0 + tok) * H_DIM);
    __bf16* orow = Xaug + (size_t)(n0 + tok) * K1P;
    for (int c = t; c < H_DIM / 4; c += 256) {
      float4 v = xr[c];
      *(float4*)&sx[tok][c * 4] = v;
      bf16x4 b = {(__bf16)v.x, (__bf16)v.y, (__bf16)v.z, (__bf16)v.w};
      *(bf16x4*)(orow + c * 4) = b;
    }
  }
  __syncthreads();
  int wv = t >> 6, ln = t & 63;
  for (int idx = wv; idx < 88; idx += 4) {
    const float* wrow;
    if      (idx <  8) wrow = vAg  + (size_t)idx * H_DIM;
    else if (idx < 40) wrow = tmAg + (size_t)(idx - 8) * H_DIM;
    else if (idx < 44) wrow = rg   + (size_t)(idx - 40) * H_DIM;
    else if (idx < 52) wrow = vAu  + (size_t)(idx - 44) * H_DIM;
    else if (idx < 84) wrow = tmAu + (size_t)(idx - 52) * H_DIM;
    else               wrow = ru   + (size_t)(idx - 84) * H_DIM;
    float a0 = 0, a1 = 0, a2 = 0, a3 = 0;
    for (int j = 0; j < H_DIM / 64; ++j) {
      int h = j * 64 + ln;
      float w = wrow[h];
      a0 = fmaf(sx[0][h], w, a0);
      a1 = fmaf(sx[1][h], w, a1);
      a2 = fmaf(sx[2][h], w, a2);
      a3 = fmaf(sx[3][h], w, a3);
    }
    for (int s = 32; s > 0; s >>= 1) {
      a0 += __shfl_xor(a0, s); a1 += __shfl_xor(a1, s);
      a2 += __shfl_xor(a2, s); a3 += __shfl_xor(a3, s);
    }
    if (ln == 0) { dots[0][idx] = a0; dots[1][idx] = a1; dots[2][idx] = a2; dots[3][idx] = a3; }
  }
  __syncthreads();
  for (int pass = 0; pass < 2; ++pass) {
    int tok = (t >> 7) + pass * 2;
    int s = t & 127;
    const float* dd = dots[tok];
    bool img = read_mask(mask, n0 + tok, okI, okF);
    float c = 0.f;
    if (s < 80) {
      if (s < 40) {  // gate coeffs: [0,8) LoRA, [8,40) MoE e*8+r
        if (img) { if (s < 8) c = dd[s]; }
        else if (s >= 8) {
          float l0 = dd[40], l1 = dd[41], l2 = dd[42], l3 = dd[43];
          float mx = fmaxf(fmaxf(l0, l1), fmaxf(l2, l3));
          float e0 = __expf(l0 - mx), e1 = __expf(l1 - mx), e2 = __expf(l2 - mx), e3 = __expf(l3 - mx);
          float inv = 1.f / (e0 + e1 + e2 + e3);
          int e = (s - 8) >> 3;
          float ge = (e == 0 ? e0 : e == 1 ? e1 : e == 2 ? e2 : e3) * inv;
          c = ge * dd[s];
        }
      } else {       // up coeffs
        int s2 = s - 40;
        if (img) { if (s2 < 8) c = dd[44 + s2]; }
        else if (s2 >= 8) {
          float l0 = dd[84], l1 = dd[85], l2 = dd[86], l3 = dd[87];
          float mx = fmaxf(fmaxf(l0, l1), fmaxf(l2, l3));
          float e0 = __expf(l0 - mx), e1 = __expf(l1 - mx), e2 = __expf(l2 - mx), e3 = __expf(l3 - mx);
          float inv = 1.f / (e0 + e1 + e2 + e3);
          int e = (s2 - 8) >> 3;
          float ge = (e == 0 ? e0 : e == 1 ? e1 : e == 2 ? e2 : e3) * inv;
          c = ge * dd[44 + s2];
        }
      }
    }
    Xaug[(size_t)(n0 + tok) * K1P + H_DIM + s] = (__bf16)c;
  }
}

// ---------------------------------------------------------------------------
// prep_x2: down-proj coeffs from inter (bf16 rows already in X2)
// ---------------------------------------------------------------------------
__global__ __launch_bounds__(256)
void prep_x2(const void* __restrict__ mask, const float* __restrict__ vAd,
             const float* __restrict__ tmAd, const float* __restrict__ rd,
             __bf16* __restrict__ X2) {
  __shared__ __align__(16) __bf16 si[4][I_DIM];
  __shared__ float dots[4][44];
  __shared__ int okI, okF;
  int t = threadIdx.x, n0 = blockIdx.x * 4;
  if (t == 0) { okI = 1; okF = 1; }
  __syncthreads();
  detect_mask(mask, t, &okI, &okF);
  for (int tok = 0; tok < 4; ++tok) {
    const bf16x8* xr = (const bf16x8*)(X2 + (size_t)(n0 + tok) * K2P);
    bf16x8* srow = (bf16x8*)&si[tok][0];
    for (int c = t; c < I_DIM / 8; c += 256) srow[c] = xr[c];
  }
  __syncthreads();
  int wv = t >> 6, ln = t & 63;
  for (int idx = wv; idx < 44; idx += 4) {
    const float* wrow = (idx < 8)  ? vAd  + (size_t)idx * I_DIM
                      : (idx < 40) ? tmAd + (size_t)(idx - 8) * I_DIM
                                   : rd   + (size_t)(idx - 40) * I_DIM;
    float a0 = 0, a1 = 0, a2 = 0, a3 = 0;
    for (int j = 0; j < I_DIM / 64; ++j) {
      int h = j * 64 + ln;
      float w = wrow[h];
      a0 = fmaf((float)si[0][h], w, a0);
      a1 = fmaf((float)si[1][h], w, a1);
      a2 = fmaf((float)si[2][h], w, a2);
      a3 = fmaf((float)si[3][h], w, a3);
    }
    for (int s = 32; s > 0; s >>= 1) {
      a0 += __shfl_xor(a0, s); a1 += __shfl_xor(a1, s);
      a2 += __shfl_xor(a2, s); a3 += __shfl_xor(a3, s);
    }
    if (ln == 0) { dots[0][idx] = a0; dots[1][idx] = a1; dots[2][idx] = a2; dots[3][idx] = a3; }
  }
  __syncthreads();
  for (int pass = 0; pass < 2; ++pass) {
    int tok = (t >> 7) + pass * 2;
    int s = t & 127;
    const float* dd = dots[tok];
    bool img = read_mask(mask, n0 + tok, okI, okF);
    float c = 0.f;
    if (s < 40) {
      if (img) { if (s < 8) c = dd[s]; }
      else if (s >= 8) {
        float l0 = dd[40], l1 = dd[41], l2 = dd[42], l3 = dd[43];
        float mx = fmaxf(fmaxf(l0, l1), fmaxf(l2, l3));
        float e0 = __expf(l0 - mx), e1 = __expf(l1 - mx), e2 = __expf(l2 - mx), e3 = __expf(l3 - mx);
        float inv = 1.f / (e0 + e1 + e2 + e3);
        int e = (s - 8) >> 3;
        float ge = (e == 0 ? e0 : e == 1 ? e1 : e == 2 ? e2 : e3) * inv;
        c = ge * dd[s];
      }
    }
    X2[(size_t)(n0 + tok) * K2P + I_DIM + s] = (__bf16)c;
  }
}

// ---------------------------------------------------------------------------
// gemm_gateup: 128x128 tile, BK=32, 4 waves, dual accumulators (gate & up),
// epilogue silu(gate)*up -> bf16 into X2 (K2P-strided rows).
// ---------------------------------------------------------------------------
__global__ __launch_bounds__(256)
void gemm_gateup(const __bf16* __restrict__ A, const __bf16* __restrict__ Bg,
                 const __bf16* __restrict__ Bu, __bf16* __restrict__ X2) {
  __shared__ __align__(16) __bf16 sA[128 * 32];
  __shared__ __align__(16) __bf16 sG[128 * 32];
  __shared__ __align__(16) __bf16 sU[128 * 32];
  int t = threadIdx.x;
  int wv = t >> 6, ln = t & 63;
  int wr = wv >> 1, wc = wv & 1;
  int lrow = ln & 15, kq = ln >> 4;
  int m0 = blockIdx.y * 128, n0 = blockIdx.x * 128;

  f32x4 zero = {0.f, 0.f, 0.f, 0.f};
  f32x4 accg[4][4], accu[4][4];
#pragma unroll
  for (int mi = 0; mi < 4; ++mi)
#pragma unroll
    for (int ni = 0; ni < 4; ++ni) { accg[mi][ni] = zero; accu[mi][ni] = zero; }

  int row0 = t >> 2, c0 = (t & 3) * 8;
  int row1 = (256 + t) >> 2, c1 = ((256 + t) & 3) * 8;
  const __bf16* a0p = A  + (size_t)(m0 + row0) * K1P + c0;
  const __bf16* a1p = A  + (size_t)(m0 + row1) * K1P + c1;
  const __bf16* g0p = Bg + (size_t)(n0 + row0) * K1P + c0;
  const __bf16* g1p = Bg + (size_t)(n0 + row1) * K1P + c1;
  const __bf16* u0p = Bu + (size_t)(n0 + row0) * K1P + c0;
  const __bf16* u1p = Bu + (size_t)(n0 + row1) * K1P + c1;
  const char* lA0 = (const char*)sA + (wv * 64) * 16;
  const char* lA1 = (const char*)sA + (256 + wv * 64) * 16;
  const char* lG0 = (const char*)sG + (wv * 64) * 16;
  const char* lG1 = (const char*)sG + (256 + wv * 64) * 16;
  const char* lU0 = (const char*)sU + (wv * 64) * 16;
  const char* lU1 = (const char*)sU + (256 + wv * 64) * 16;

  for (int k0 = 0; k0 < K1P; k0 += 32) {
    gload16(a0p + k0, lA0);
    gload16(a1p + k0, lA1);
    gload16(g0p + k0, lG0);
    gload16(g1p + k0, lG1);
    gload16(u0p + k0, lU0);
    gload16(u1p + k0, lU1);
    __syncthreads();   // drains vmcnt -> LDS tiles ready
    bf16x8 a[4];
#pragma unroll
    for (int mi = 0; mi < 4; ++mi)
      a[mi] = *(const bf16x8*)&sA[(wr * 64 + mi * 16 + lrow) * 32 + kq * 8];
#pragma unroll
    for (int ni = 0; ni < 4; ++ni) {
      bf16x8 b = *(const bf16x8*)&sG[(wc * 64 + ni * 16 + lrow) * 32 + kq * 8];
#pragma unroll
      for (int mi = 0; mi < 4; ++mi)
        accg[mi][ni] = __builtin_amdgcn_mfma_f32_16x16x32_bf16(a[mi], b, accg[mi][ni], 0, 0, 0);
    }
#pragma unroll
    for (int ni = 0; ni < 4; ++ni) {
      bf16x8 b = *(const bf16x8*)&sU[(wc * 64 + ni * 16 + lrow) * 32 + kq * 8];
#pragma unroll
      for (int mi = 0; mi < 4; ++mi)
        accu[mi][ni] = __builtin_amdgcn_mfma_f32_16x16x32_bf16(a[mi], b, accu[mi][ni], 0, 0, 0);
    }
    __syncthreads();   // all reads done before next stage overwrites LDS
  }

#pragma unroll
  for (int mi = 0; mi < 4; ++mi) {
#pragma unroll
    for (int q = 0; q < 4; ++q) {
      int tok = m0 + wr * 64 + mi * 16 + kq * 4 + q;
      __bf16* orow = X2 + (size_t)tok * K2P + n0 + wc * 64 + lrow;
#pragma unroll
      for (int ni = 0; ni < 4; ++ni) {
        float g = accg[mi][ni][q], u = accu[mi][ni][q];
        float sg = g / (1.f + __expf(-g));
        orow[ni * 16] = (__bf16)(sg * u);
      }
    }
  }
}

// ---------------------------------------------------------------------------
// gemm_down: 128x128 tile, BK=32, single accumulator, fp32 out.
// ---------------------------------------------------------------------------
__global__ __launch_bounds__(256)
void gemm_down(const __bf16* __restrict__ A, const __bf16* __restrict__ B,
               float* __restrict__ out) {
  __shared__ __align__(16) __bf16 sA[128 * 32];
  __shared__ __align__(16) __bf16 sB[128 * 32];
  int t = threadIdx.x;
  int wv = t >> 6, ln = t & 63;
  int wr = wv >> 1, wc = wv & 1;
  int lrow = ln & 15, kq = ln >> 4;
  int m0 = blockIdx.y * 128, n0 = blockIdx.x * 128;

  f32x4 zero = {0.f, 0.f, 0.f, 0.f};
  f32x4 acc[4][4];
#pragma unroll
  for (int mi = 0; mi < 4; ++mi)
#pragma unroll
    for (int ni = 0; ni < 4; ++ni) acc[mi][ni] = zero;

  int row0 = t >> 2, c0 = (t & 3) * 8;
  int row1 = (256 + t) >> 2, c1 = ((256 + t) & 3) * 8;
  const __bf16* a0p = A + (size_t)(m0 + row0) * K2P + c0;
  const __bf16* a1p = A + (size_t)(m0 + row1) * K2P + c1;
  const __bf16* b0p = B + (size_t)(n0 + row0) * K2P + c0;
  const __bf16* b1p = B + (size_t)(n0 + row1) * K2P + c1;
  const char* lA0 = (const char*)sA + (wv * 64) * 16;
  const char* lA1 = (const char*)sA + (256 + wv * 64) * 16;
  const char* lB0 = (const char*)sB + (wv * 64) * 16;
  const char* lB1 = (const char*)sB + (256 + wv * 64) * 16;

  for (int k0 = 0; k0 < K2P; k0 += 32) {
    gload16(a0p + k0, lA0);
    gload16(a1p + k0, lA1);
    gload16(b0p + k0, lB0);
    gload16(b1p + k0, lB1);
    __syncthreads();
    bf16x8 a[4];
#pragma unroll
    for (int mi = 0; mi < 4; ++mi)
      a[mi] = *(const bf16x8*)&sA[(wr * 64 + mi * 16 + lrow) * 32 + kq * 8];
#pragma unroll
    for (int ni = 0; ni < 4; ++ni) {
      bf16x8 b = *(const bf16x8*)&sB[(wc * 64 + ni * 16 + lrow) * 32 + kq * 8];
#pragma unroll
      for (int mi = 0; mi < 4; ++mi)
        acc[mi][ni] = __builtin_amdgcn_mfma_f32_16x16x32_bf16(a[mi], b, acc[mi][ni], 0, 0, 0);
    }
    __syncthreads();
  }

#pragma unroll
  for (int mi = 0; mi < 4; ++mi) {
#pragma unroll
    for (int q = 0; q < 4; ++q) {
      int tok = m0 + wr * 64 + mi * 16 + kq * 4 + q;
      float* orow = out + (size_t)tok * H_DIM + n0 + wc * 64 + lrow;
#pragma unroll
      for (int ni = 0; ni < 4; ++ni) orow[ni * 16] = acc[mi][ni][q];
    }
  }
}

// ---------------------------------------------------------------------------
extern "C" void kernel_launch(void* const* d_in, const int* in_sizes, int n_in,
                              void* d_out, int out_size, void* d_ws, size_t ws_size,
                              hipStream_t stream) {
  const float* x    = (const float*)d_in[0];
  const void*  mask = d_in[1];
  const float* Wg   = (const float*)d_in[2];
  const float* Wu   = (const float*)d_in[3];
  const float* Wd   = (const float*)d_in[4];
  const float* vAg  = (const float*)d_in[5];
  const float* vBg  = (const float*)d_in[6];
  const float* vAu  = (const float*)d_in[7];
  const float* vBu  = (const float*)d_in[8];
  const float* vAd  = (const float*)d_in[9];
  const float* vBd  = (const float*)d_in[10];
  const float* rg   = (const float*)d_in[11];
  const float* tmAg = (const float*)d_in[12];
  const float* tmBg = (const float*)d_in[13];
  const float* ru   = (const float*)d_in[14];
  const float* tmAu = (const float*)d_in[15];
  const float* tmBu = (const float*)d_in[16];
  const float* rd   = (const float*)d_in[17];
  const float* tmAd = (const float*)d_in[18];
  const float* tmBd = (const float*)d_in[19];

  // workspace layout (bytes): 403,046,400 total
  char* ws = (char*)d_ws;
  __bf16* Xaug = (__bf16*)(ws);                    // 4096*4224*2  = 34,603,008
  __bf16* Wga  = (__bf16*)(ws + 34603008);         // 11008*4224*2 = 92,995,584
  __bf16* Wua  = (__bf16*)(ws + 127598592);        // 11008*4224*2
  __bf16* X2   = (__bf16*)(ws + 220594176);        // 4096*11136*2 = 91,226,112
  __bf16* Wda  = (__bf16*)(ws + 311820288);        // 4096*11136*2

  prep_w1<<<I_DIM, 256, 0, stream>>>(Wg, Wu, vBg, tmBg, vBu, tmBu, Wga, Wua);
  prep_wd<<<H_DIM, 256, 0, stream>>>(Wd, vBd, tmBd, Wda);
  prep_x<<<N_TOK / 4, 256, 0, stream>>>(x, mask, vAg, tmAg, rg, vAu, tmAu, ru, Xaug);
  gemm_gateup<<<dim3(I_DIM / 128, N_TOK / 128), 256, 0, stream>>>(Xaug, Wga, Wua, X2);
  prep_x2<<<N_TOK / 4, 256, 0, stream>>>(mask, vAd, tmAd, rd, X2);
  gemm_down<<<dim3(H_DIM / 128, N_TOK / 128), 256, 0, stream>>>(X2, Wda, (float*)d_out);
}

// Round 2
// 1987.784 us; speedup vs baseline: 1.5391x; 1.5391x over previous
//
#include <hip/hip_runtime.h>
#include <hip/hip_bf16.h>
#include <stdint.h>

// ---------------------------------------------------------------------------
// MoDEChameleonMLP, round 2: 256x256 8-wave phased GEMM template (T2+T3+T4+T5)
//   GEMM1: [4096,4224] x [22016,4224]^T -> C1 bf16 [4096,22016] (gate|up)
//   silumul: silu(gate)*up -> X2 cols 0..11007
//   GEMM2: [4096,11136] x [4096,11136]^T -> out fp32 [4096,4096]
// Deltas folded into K as augmented columns (K1P=4224, K2P=11136).
// ---------------------------------------------------------------------------

#define H_DIM 4096
#define I_DIM 11008
#define N_TOK 4096
#define R_RANK 8
#define K1P 4224
#define K2P 11136
#define N1  22016   // gate|up concatenated output cols

typedef __attribute__((ext_vector_type(8))) __bf16 bf16x8;
typedef __attribute__((ext_vector_type(4))) __bf16 bf16x4;
typedef __attribute__((ext_vector_type(4))) float  f32x4;

__device__ __forceinline__ void gload16(const void* g, const void* lds_wave_base) {
  auto gp = (const __attribute__((address_space(1))) void*)(uintptr_t)g;
  auto lp = (__attribute__((address_space(3))) void*)(uintptr_t)lds_wave_base;
  __builtin_amdgcn_global_load_lds(gp, lp, 16, 0, 0);
}

#define BAR()   asm volatile("s_barrier" ::: "memory")
#define LGKM0() do { asm volatile("s_waitcnt lgkmcnt(0)" ::: "memory"); \
                     __builtin_amdgcn_sched_barrier(0); } while (0)

// ---- mask dtype probe ------------------------------------------------------
__device__ __forceinline__ void detect_mask(const void* mask, int t, int* okI, int* okF) {
  const unsigned int* mi = (const unsigned int*)mask;
  int bad_i = 0, bad_f = 0;
  for (int idx = t; idx < 1024; idx += 256) {
    unsigned v = mi[idx];
    bad_i |= !(v == 0u || v == 1u);
    bad_f |= !(v == 0u || v == 0x3f800000u);
  }
  if (bad_i) *okI = 0;
  if (bad_f) *okF = 0;
}
__device__ __forceinline__ bool read_mask(const void* mask, int n, int okI, int okF) {
  if (okI) return ((const int*)mask)[n] != 0;
  if (okF) return ((const float*)mask)[n] != 0.0f;
  return ((const unsigned char*)mask)[n] != 0;
}

// ---------------------------------------------------------------------------
// prep_w1 / prep_wd / prep_x / prep_x2 : unchanged from round 1 (verified)
// ---------------------------------------------------------------------------
__global__ __launch_bounds__(256)
void prep_w1(const float* __restrict__ Wg, const float* __restrict__ Wu,
             const float* __restrict__ vBg, const float* __restrict__ tmBg,
             const float* __restrict__ vBu, const float* __restrict__ tmBu,
             __bf16* __restrict__ Wga, __bf16* __restrict__ Wua) {
  int i = blockIdx.x, t = threadIdx.x;
  const float4* g4 = (const float4*)(Wg + (size_t)i * H_DIM);
  const float4* u4 = (const float4*)(Wu + (size_t)i * H_DIM);
  __bf16* og = Wga + (size_t)i * K1P;
  __bf16* ou = Wua + (size_t)i * K1P;
  for (int c = t; c < H_DIM / 4; c += 256) {
    float4 v = g4[c];
    bf16x4 b = {(__bf16)v.x, (__bf16)v.y, (__bf16)v.z, (__bf16)v.w};
    *(bf16x4*)(og + c * 4) = b;
    v = u4[c];
    bf16x4 b2 = {(__bf16)v.x, (__bf16)v.y, (__bf16)v.z, (__bf16)v.w};
    *(bf16x4*)(ou + c * 4) = b2;
  }
  if (t < 128) {
    float gv = 0.f, uv = 0.f;
    if (t < 8) gv = 2.f * vBg[i * R_RANK + t];
    else if (t < 40) { int e = (t - 8) >> 3, r = (t - 8) & 7;
      gv = 2.f * tmBg[((size_t)e * I_DIM + i) * R_RANK + r]; }
    if (t >= 40 && t < 48) uv = 2.f * vBu[i * R_RANK + (t - 40)];
    else if (t >= 48 && t < 80) { int e = (t - 48) >> 3, r = (t - 48) & 7;
      uv = 2.f * tmBu[((size_t)e * I_DIM + i) * R_RANK + r]; }
    og[H_DIM + t] = (__bf16)gv;
    ou[H_DIM + t] = (__bf16)uv;
  }
}

__global__ __launch_bounds__(256)
void prep_wd(const float* __restrict__ Wd, const float* __restrict__ vBd,
             const float* __restrict__ tmBd, __bf16* __restrict__ Wda) {
  int o = blockIdx.x, t = threadIdx.x;
  const float4* w4 = (const float4*)(Wd + (size_t)o * I_DIM);
  __bf16* orow = Wda + (size_t)o * K2P;
  for (int c = t; c < I_DIM / 4; c += 256) {
    float4 v = w4[c];
    bf16x4 b = {(__bf16)v.x, (__bf16)v.y, (__bf16)v.z, (__bf16)v.w};
    *(bf16x4*)(orow + c * 4) = b;
  }
  if (t < 128) {
    float v = 0.f;
    if (t < 8) v = 2.f * vBd[o * R_RANK + t];
    else if (t < 40) { int e = (t - 8) >> 3, r = (t - 8) & 7;
      v = 2.f * tmBd[((size_t)e * H_DIM + o) * R_RANK + r]; }
    orow[I_DIM + t] = (__bf16)v;
  }
}

__global__ __launch_bounds__(256)
void prep_x(const float* __restrict__ x, const void* __restrict__ mask,
            const float* __restrict__ vAg, const float* __restrict__ tmAg, const float* __restrict__ rg,
            const float* __restrict__ vAu, const float* __restrict__ tmAu, const float* __restrict__ ru,
            __bf16* __restrict__ Xaug) {
  __shared__ __align__(16) float sx[4][H_DIM];
  __shared__ float dots[4][88];
  __shared__ int okI, okF;
  int t = threadIdx.x, n0 = blockIdx.x * 4;
  if (t == 0) { okI = 1; okF = 1; }
  __syncthreads();
  detect_mask(mask, t, &okI, &okF);
  for (int tok = 0; tok < 4; ++tok) {
    const float4* xr = (const float4*)(x + (size_t)(n0 + tok) * H_DIM);
    __bf16* orow = Xaug + (size_t)(n0 + tok) * K1P;
    for (int c = t; c < H_DIM / 4; c += 256) {
      float4 v = xr[c];
      *(float4*)&sx[tok][c * 4] = v;
      bf16x4 b = {(__bf16)v.x, (__bf16)v.y, (__bf16)v.z, (__bf16)v.w};
      *(bf16x4*)(orow + c * 4) = b;
    }
  }
  __syncthreads();
  int wv = t >> 6, ln = t & 63;
  for (int idx = wv; idx < 88; idx += 4) {
    const float* wrow;
    if      (idx <  8) wrow = vAg  + (size_t)idx * H_DIM;
    else if (idx < 40) wrow = tmAg + (size_t)(idx - 8) * H_DIM;
    else if (idx < 44) wrow = rg   + (size_t)(idx - 40) * H_DIM;
    else if (idx < 52) wrow = vAu  + (size_t)(idx - 44) * H_DIM;
    else if (idx < 84) wrow = tmAu + (size_t)(idx - 52) * H_DIM;
    else               wrow = ru   + (size_t)(idx - 84) * H_DIM;
    float a0 = 0, a1 = 0, a2 = 0, a3 = 0;
    for (int j = 0; j < H_DIM / 64; ++j) {
      int h = j * 64 + ln;
      float w = wrow[h];
      a0 = fmaf(sx[0][h], w, a0);
      a1 = fmaf(sx[1][h], w, a1);
      a2 = fmaf(sx[2][h], w, a2);
      a3 = fmaf(sx[3][h], w, a3);
    }
    for (int s = 32; s > 0; s >>= 1) {
      a0 += __shfl_xor(a0, s); a1 += __shfl_xor(a1, s);
      a2 += __shfl_xor(a2, s); a3 += __shfl_xor(a3, s);
    }
    if (ln == 0) { dots[0][idx] = a0; dots[1][idx] = a1; dots[2][idx] = a2; dots[3][idx] = a3; }
  }
  __syncthreads();
  for (int pass = 0; pass < 2; ++pass) {
    int tok = (t >> 7) + pass * 2;
    int s = t & 127;
    const float* dd = dots[tok];
    bool img = read_mask(mask, n0 + tok, okI, okF);
    float c = 0.f;
    if (s < 80) {
      if (s < 40) {
        if (img) { if (s < 8) c = dd[s]; }
        else if (s >= 8) {
          float l0 = dd[40], l1 = dd[41], l2 = dd[42], l3 = dd[43];
          float mx = fmaxf(fmaxf(l0, l1), fmaxf(l2, l3));
          float e0 = __expf(l0 - mx), e1 = __expf(l1 - mx), e2 = __expf(l2 - mx), e3 = __expf(l3 - mx);
          float inv = 1.f / (e0 + e1 + e2 + e3);
          int e = (s - 8) >> 3;
          float ge = (e == 0 ? e0 : e == 1 ? e1 : e == 2 ? e2 : e3) * inv;
          c = ge * dd[s];
        }
      } else {
        int s2 = s - 40;
        if (img) { if (s2 < 8) c = dd[44 + s2]; }
        else if (s2 >= 8) {
          float l0 = dd[84], l1 = dd[85], l2 = dd[86], l3 = dd[87];
          float mx = fmaxf(fmaxf(l0, l1), fmaxf(l2, l3));
          float e0 = __expf(l0 - mx), e1 = __expf(l1 - mx), e2 = __expf(l2 - mx), e3 = __expf(l3 - mx);
          float inv = 1.f / (e0 + e1 + e2 + e3);
          int e = (s2 - 8) >> 3;
          float ge = (e == 0 ? e0 : e == 1 ? e1 : e == 2 ? e2 : e3) * inv;
          c = ge * dd[44 + s2];
        }
      }
    }
    Xaug[(size_t)(n0 + tok) * K1P + H_DIM + s] = (__bf16)c;
  }
}

__global__ __launch_bounds__(256)
void prep_x2(const void* __restrict__ mask, const float* __restrict__ vAd,
             const float* __restrict__ tmAd, const float* __restrict__ rd,
             __bf16* __restrict__ X2) {
  __shared__ __align__(16) __bf16 si[4][I_DIM];
  __shared__ float dots[4][44];
  __shared__ int okI, okF;
  int t = threadIdx.x, n0 = blockIdx.x * 4;
  if (t == 0) { okI = 1; okF = 1; }
  __syncthreads();
  detect_mask(mask, t, &okI, &okF);
  for (int tok = 0; tok < 4; ++tok) {
    const bf16x8* xr = (const bf16x8*)(X2 + (size_t)(n0 + tok) * K2P);
    bf16x8* srow = (bf16x8*)&si[tok][0];
    for (int c = t; c < I_DIM / 8; c += 256) srow[c] = xr[c];
  }
  __syncthreads();
  int wv = t >> 6, ln = t & 63;
  for (int idx = wv; idx < 44; idx += 4) {
    const float* wrow = (idx < 8)  ? vAd  + (size_t)idx * I_DIM
                      : (idx < 40) ? tmAd + (size_t)(idx - 8) * I_DIM
                                   : rd   + (size_t)(idx - 40) * I_DIM;
    float a0 = 0, a1 = 0, a2 = 0, a3 = 0;
    for (int j = 0; j < I_DIM / 64; ++j) {
      int h = j * 64 + ln;
      float w = wrow[h];
      a0 = fmaf((float)si[0][h], w, a0);
      a1 = fmaf((float)si[1][h], w, a1);
      a2 = fmaf((float)si[2][h], w, a2);
      a3 = fmaf((float)si[3][h], w, a3);
    }
    for (int s = 32; s > 0; s >>= 1) {
      a0 += __shfl_xor(a0, s); a1 += __shfl_xor(a1, s);
      a2 += __shfl_xor(a2, s); a3 += __shfl_xor(a3, s);
    }
    if (ln == 0) { dots[0][idx] = a0; dots[1][idx] = a1; dots[2][idx] = a2; dots[3][idx] = a3; }
  }
  __syncthreads();
  for (int pass = 0; pass < 2; ++pass) {
    int tok = (t >> 7) + pass * 2;
    int s = t & 127;
    const float* dd = dots[tok];
    bool img = read_mask(mask, n0 + tok, okI, okF);
    float c = 0.f;
    if (s < 40) {
      if (img) { if (s < 8) c = dd[s]; }
      else if (s >= 8) {
        float l0 = dd[40], l1 = dd[41], l2 = dd[42], l3 = dd[43];
        float mx = fmaxf(fmaxf(l0, l1), fmaxf(l2, l3));
        float e0 = __expf(l0 - mx), e1 = __expf(l1 - mx), e2 = __expf(l2 - mx), e3 = __expf(l3 - mx);
        float inv = 1.f / (e0 + e1 + e2 + e3);
        int e = (s - 8) >> 3;
        float ge = (e == 0 ? e0 : e == 1 ? e1 : e == 2 ? e2 : e3) * inv;
        c = ge * dd[s];
      }
    }
    X2[(size_t)(n0 + tok) * K2P + I_DIM + s] = (__bf16)c;
  }
}

// ---------------------------------------------------------------------------
// 256x256 BK=64 8-wave phased GEMM. A:[M,KS], B:[N,KS] row-major, C=A*B^T.
// LDS 128KB: A0@0, B0@32768, A1@65536, B1@98304. T2 swizzle byte^=((row&7)<<4)
// via inverse-swizzled global source (linear gload_lds dest) + swizzled read.
// Counted vmcnt(8) once per K-tile at phase-4 end, before the barrier.
// ---------------------------------------------------------------------------
template<int MH, int NH>
__device__ __forceinline__ void mfmaq(f32x4 (&acc)[8][4], const bf16x8 (&av)[4][2],
                                      const bf16x8 (&bv)[2][2]) {
#pragma unroll
  for (int kk = 0; kk < 2; ++kk)
#pragma unroll
    for (int j = 0; j < 2; ++j)
#pragma unroll
      for (int i = 0; i < 4; ++i)
        acc[MH * 4 + i][NH * 2 + j] = __builtin_amdgcn_mfma_f32_16x16x32_bf16(
            av[i][kk], bv[j][kk], acc[MH * 4 + i][NH * 2 + j], 0, 0, 0);
}

template<int KS, int NT, int GN, typename OutT, int OSTR>
__global__ __launch_bounds__(512, 2)
void gemm256(const __bf16* __restrict__ A, const __bf16* __restrict__ Bm,
             OutT* __restrict__ C) {
  __shared__ __align__(16) char lds[131072];

  int t = threadIdx.x;
  int w = t >> 6, l = t & 63;
  int wm = w >> 2, wn = w & 3;
  int lrow = l & 15, kq = l >> 4;

  // XCD-bijective swizzle (gridDim.x % 8 == 0 for both instantiations)
  int nwg = gridDim.x, bid = blockIdx.x;
  int swz = (bid & 7) * (nwg >> 3) + (bid >> 3);
  int tm = swz / GN, tn = swz % GN;
  int m0 = tm * 256, n0 = tn * 256;

  // staging: per-lane inverse-swizzled global source; linear LDS dest
  int grow = (t >> 3) & 7;
  int gcole = ((t & 7) ^ grow) << 3;                 // swizzled col (elements)
  const __bf16* gA0 = A  + (size_t)(m0 + w * 8 + grow) * KS + gcole;
  const __bf16* gB0 = Bm + (size_t)(n0 + w * 8 + grow) * KS + gcole;
  char* ldsA0 = lds + w * 1024;                      // + buf*65536 + c*8192
  char* ldsB0 = lds + 32768 + w * 1024;

  auto stageA = [&](int buf, int tt, int c) {
    gload16(gA0 + (size_t)c * (64 * KS) + (size_t)tt * 64,
            ldsA0 + buf * 65536 + c * 8192);
  };
  auto stageB = [&](int buf, int tt, int c) {
    gload16(gB0 + (size_t)c * (64 * KS) + (size_t)tt * 64,
            ldsB0 + buf * 65536 + c * 8192);
  };

  // swizzled ds_read addressing
  int aBase = (wm * 128 + lrow) * 128;
  int bBase = (wn * 64 + lrow) * 128;
  int sw    = (lrow & 7) << 4;
  int col0  = (kq * 16) ^ sw;
  int col1  = (64 + kq * 16) ^ sw;

  f32x4 acc[8][4];
#pragma unroll
  for (int i = 0; i < 8; ++i)
#pragma unroll
    for (int j = 0; j < 4; ++j) acc[i][j] = (f32x4){0.f, 0.f, 0.f, 0.f};

  // prologue: tiles 0 -> buf0, 1 -> buf1
#pragma unroll
  for (int c = 0; c < 4; ++c) { stageA(0, 0, c); stageB(0, 0, c); }
#pragma unroll
  for (int c = 0; c < 4; ++c) { stageA(1, 1, c); stageB(1, 1, c); }
  asm volatile("s_waitcnt vmcnt(8)" ::: "memory");
  BAR();

  int cur = 0;
  for (int tt = 0; tt < NT; ++tt, cur ^= 1) {
    const char* sa = lds + (cur ? 65536 : 0);
    const char* sb = sa + 32768;
    int t2 = tt + 2;
    bool st = t2 < NT;
    bf16x8 aF[4][2], b0[2][2], b1[2][2];

    // P1: A(mh0) + B(nh0) reads -> Q00
#pragma unroll
    for (int i = 0; i < 4; ++i) {
      aF[i][0] = *(const bf16x8*)(sa + aBase + i * 2048 + col0);
      aF[i][1] = *(const bf16x8*)(sa + aBase + i * 2048 + col1);
    }
#pragma unroll
    for (int j = 0; j < 2; ++j) {
      b0[j][0] = *(const bf16x8*)(sb + bBase + j * 2048 + col0);
      b0[j][1] = *(const bf16x8*)(sb + bBase + j * 2048 + col1);
    }
    BAR(); LGKM0();
    __builtin_amdgcn_s_setprio(1);
    mfmaq<0, 0>(acc, aF, b0);
    __builtin_amdgcn_s_setprio(0);
    BAR();

    // P2: stage A[t+2] chunks 0,2 (freed by P1) ; B(nh1) reads -> Q01
    if (st) { stageA(cur, t2, 0); stageA(cur, t2, 2); }
#pragma unroll
    for (int j = 0; j < 2; ++j) {
      b1[j][0] = *(const bf16x8*)(sb + bBase + (2 + j) * 2048 + col0);
      b1[j][1] = *(const bf16x8*)(sb + bBase + (2 + j) * 2048 + col1);
    }
    BAR(); LGKM0();
    __builtin_amdgcn_s_setprio(1);
    mfmaq<0, 1>(acc, aF, b1);
    __builtin_amdgcn_s_setprio(0);
    BAR();

    // P3: stage B[t+2] chunks 0,1 (B freed by P2) ; A(mh1) reads -> Q10
    if (st) { stageB(cur, t2, 0); stageB(cur, t2, 1); }
#pragma unroll
    for (int i = 0; i < 4; ++i) {
      aF[i][0] = *(const bf16x8*)(sa + aBase + (4 + i) * 2048 + col0);
      aF[i][1] = *(const bf16x8*)(sa + aBase + (4 + i) * 2048 + col1);
    }
    BAR(); LGKM0();
    __builtin_amdgcn_s_setprio(1);
    mfmaq<1, 0>(acc, aF, b0);
    __builtin_amdgcn_s_setprio(0);
    BAR();

    // P4: stage B[t+2] 2,3 + A[t+2] 1,3 (freed by P2/P3); Q11; counted vmcnt
    if (st) { stageB(cur, t2, 2); stageB(cur, t2, 3);
              stageA(cur, t2, 1); stageA(cur, t2, 3); }
    __builtin_amdgcn_s_setprio(1);
    mfmaq<1, 1>(acc, aF, b1);
    __builtin_amdgcn_s_setprio(0);
    if (st) asm volatile("s_waitcnt vmcnt(8)" ::: "memory");
    else    asm volatile("s_waitcnt vmcnt(0)" ::: "memory");
    BAR();
  }

  // epilogue: C[m][n], row = m0+wm*128+mi*16+kq*4+q, col = n0+wn*64+ni*16+lrow
  int r0 = m0 + wm * 128 + kq * 4;
  int c0 = n0 + wn * 64 + lrow;
#pragma unroll
  for (int mi = 0; mi < 8; ++mi) {
#pragma unroll
    for (int q = 0; q < 4; ++q) {
      OutT* p = C + (size_t)(r0 + mi * 16 + q) * OSTR + c0;
#pragma unroll
      for (int ni = 0; ni < 4; ++ni) p[ni * 16] = (OutT)acc[mi][ni][q];
    }
  }
}

// ---------------------------------------------------------------------------
// silumul: X2[:, :11008] = silu(C1[:, :11008]) * C1[:, 11008:22016]
// ---------------------------------------------------------------------------
__global__ __launch_bounds__(256)
void silumul(const __bf16* __restrict__ C1, __bf16* __restrict__ X2) {
  int row = blockIdx.x;
  const __bf16* g = C1 + (size_t)row * N1;
  const __bf16* u = g + I_DIM;
  __bf16* o = X2 + (size_t)row * K2P;
  for (int c = threadIdx.x; c < I_DIM / 8; c += 256) {
    bf16x8 gv = *(const bf16x8*)(g + c * 8);
    bf16x8 uv = *(const bf16x8*)(u + c * 8);
    bf16x8 r;
#pragma unroll
    for (int j = 0; j < 8; ++j) {
      float gf = (float)gv[j], uf = (float)uv[j];
      r[j] = (__bf16)(gf / (1.f + __expf(-gf)) * uf);
    }
    *(bf16x8*)(o + c * 8) = r;
  }
}

// ---------------------------------------------------------------------------
extern "C" void kernel_launch(void* const* d_in, const int* in_sizes, int n_in,
                              void* d_out, int out_size, void* d_ws, size_t ws_size,
                              hipStream_t stream) {
  const float* x    = (const float*)d_in[0];
  const void*  mask = d_in[1];
  const float* Wg   = (const float*)d_in[2];
  const float* Wu   = (const float*)d_in[3];
  const float* Wd   = (const float*)d_in[4];
  const float* vAg  = (const float*)d_in[5];
  const float* vBg  = (const float*)d_in[6];
  const float* vAu  = (const float*)d_in[7];
  const float* vBu  = (const float*)d_in[8];
  const float* vAd  = (const float*)d_in[9];
  const float* vBd  = (const float*)d_in[10];
  const float* rg   = (const float*)d_in[11];
  const float* tmAg = (const float*)d_in[12];
  const float* tmBg = (const float*)d_in[13];
  const float* ru   = (const float*)d_in[14];
  const float* tmAu = (const float*)d_in[15];
  const float* tmBu = (const float*)d_in[16];
  const float* rd   = (const float*)d_in[17];
  const float* tmAd = (const float*)d_in[18];
  const float* tmBd = (const float*)d_in[19];

  // workspace layout (bytes), total 400,949,248 (<= round-0's proven 403MB):
  //   Xaug 0..34,603,008 ; Wga|Wua 34,603,008..220,594,176 ;
  //   C1 220,594,176..400,949,248 ;
  //   X2 0..91,226,112 (reuses Xaug+Wga-head after gemm1) ;
  //   Wda 91,226,112..182,452,224 (reuses Wga-tail/Wua after gemm1)
  char* ws = (char*)d_ws;
  __bf16* Xaug = (__bf16*)(ws);
  __bf16* Wga  = (__bf16*)(ws + 34603008);   // + Wua contiguous after 11008 rows
  __bf16* Wua  = Wga + (size_t)I_DIM * K1P;
  __bf16* C1   = (__bf16*)(ws + 220594176);
  __bf16* X2   = (__bf16*)(ws);
  __bf16* Wda  = (__bf16*)(ws + 91226112);

  prep_w1<<<I_DIM, 256, 0, stream>>>(Wg, Wu, vBg, tmBg, vBu, tmBu, Wga, Wua);
  prep_x<<<N_TOK / 4, 256, 0, stream>>>(x, mask, vAg, tmAg, rg, vAu, tmAu, ru, Xaug);

  // GEMM1: [4096,4224] x [22016,4224]^T -> C1 ; grid 16*86 = 1376 (%8==0)
  gemm256<K1P, K1P / 64, N1 / 256, __bf16, N1>
      <<<(N_TOK / 256) * (N1 / 256), 512, 0, stream>>>(Xaug, Wga, C1);

  silumul<<<N_TOK, 256, 0, stream>>>(C1, X2);
  prep_wd<<<H_DIM, 256, 0, stream>>>(Wd, vBd, tmBd, Wda);
  prep_x2<<<N_TOK / 4, 256, 0, stream>>>(mask, vAd, tmAd, rd, X2);

  // GEMM2: [4096,11136] x [4096,11136]^T -> out fp32 ; grid 16*16 = 256
  gemm256<K2P, K2P / 64, H_DIM / 256, float, H_DIM>
      <<<(N_TOK / 256) * (H_DIM / 256), 512, 0, stream>>>(X2, Wda, (float*)d_out);
}

// Round 3
// 1954.460 us; speedup vs baseline: 1.5653x; 1.0171x over previous
//
#include <hip/hip_runtime.h>
#include <hip/hip_bf16.h>
#include <stdint.h>

// ---------------------------------------------------------------------------
// MoDEChameleonMLP, round 3:
//   GEMM1 (fused): [4096,4224] x [22016,4224]^T, B packed as interleaved
//     [128 gate | 128 up] per 256-row tile; epilogue does silu(g)*u -> X2 bf16.
//   GEMM2: [4096,11136] x [4096,11136]^T -> out fp32.
// Deltas folded into K as augmented columns (K1P=4224, K2P=11136).
// ---------------------------------------------------------------------------

#define H_DIM 4096
#define I_DIM 11008
#define N_TOK 4096
#define R_RANK 8
#define K1P 4224
#define K2P 11136

typedef __attribute__((ext_vector_type(8))) __bf16 bf16x8;
typedef __attribute__((ext_vector_type(4))) __bf16 bf16x4;
typedef __attribute__((ext_vector_type(4))) float  f32x4;

__device__ __forceinline__ void gload16(const void* g, const void* lds_wave_base) {
  auto gp = (const __attribute__((address_space(1))) void*)(uintptr_t)g;
  auto lp = (__attribute__((address_space(3))) void*)(uintptr_t)lds_wave_base;
  __builtin_amdgcn_global_load_lds(gp, lp, 16, 0, 0);
}

#define BAR()   asm volatile("s_barrier" ::: "memory")
#define LGKM0() do { asm volatile("s_waitcnt lgkmcnt(0)" ::: "memory"); \
                     __builtin_amdgcn_sched_barrier(0); } while (0)
#define LGKM4() do { asm volatile("s_waitcnt lgkmcnt(4)" ::: "memory"); \
                     __builtin_amdgcn_sched_barrier(0); } while (0)

// ---- mask dtype probe ------------------------------------------------------
__device__ __forceinline__ void detect_mask(const void* mask, int t, int* okI, int* okF) {
  const unsigned int* mi = (const unsigned int*)mask;
  int bad_i = 0, bad_f = 0;
  for (int idx = t; idx < 1024; idx += 256) {
    unsigned v = mi[idx];
    bad_i |= !(v == 0u || v == 1u);
    bad_f |= !(v == 0u || v == 0x3f800000u);
  }
  if (bad_i) *okI = 0;
  if (bad_f) *okF = 0;
}
__device__ __forceinline__ bool read_mask(const void* mask, int n, int okI, int okF) {
  if (okI) return ((const int*)mask)[n] != 0;
  if (okF) return ((const float*)mask)[n] != 0.0f;
  return ((const unsigned char*)mask)[n] != 0;
}

// ---------------------------------------------------------------------------
// prep_w1: interleaved packing. gate col i -> Wcat row (i>>7)*256 + (i&127);
//          up   col i -> Wcat row (i>>7)*256 + 128 + (i&127).
// Row content: [bf16(W) | 2*vB | 2*tmB | zeros], K1P elements.
// ---------------------------------------------------------------------------
__global__ __launch_bounds__(256)
void prep_w1(const float* __restrict__ Wg, const float* __restrict__ Wu,
             const float* __restrict__ vBg, const float* __restrict__ tmBg,
             const float* __restrict__ vBu, const float* __restrict__ tmBu,
             __bf16* __restrict__ Wcat) {
  int i = blockIdx.x, t = threadIdx.x;
  int grp = i >> 7, within = i & 127;
  const float4* g4 = (const float4*)(Wg + (size_t)i * H_DIM);
  const float4* u4 = (const float4*)(Wu + (size_t)i * H_DIM);
  __bf16* og = Wcat + (size_t)(grp * 256 + within) * K1P;
  __bf16* ou = Wcat + (size_t)(grp * 256 + 128 + within) * K1P;
  for (int c = t; c < H_DIM / 4; c += 256) {
    float4 v = g4[c];
    bf16x4 b = {(__bf16)v.x, (__bf16)v.y, (__bf16)v.z, (__bf16)v.w};
    *(bf16x4*)(og + c * 4) = b;
    v = u4[c];
    bf16x4 b2 = {(__bf16)v.x, (__bf16)v.y, (__bf16)v.z, (__bf16)v.w};
    *(bf16x4*)(ou + c * 4) = b2;
  }
  if (t < 128) {
    float gv = 0.f, uv = 0.f;
    if (t < 8) gv = 2.f * vBg[i * R_RANK + t];
    else if (t < 40) { int e = (t - 8) >> 3, r = (t - 8) & 7;
      gv = 2.f * tmBg[((size_t)e * I_DIM + i) * R_RANK + r]; }
    if (t >= 40 && t < 48) uv = 2.f * vBu[i * R_RANK + (t - 40)];
    else if (t >= 48 && t < 80) { int e = (t - 48) >> 3, r = (t - 48) & 7;
      uv = 2.f * tmBu[((size_t)e * I_DIM + i) * R_RANK + r]; }
    og[H_DIM + t] = (__bf16)gv;
    ou[H_DIM + t] = (__bf16)uv;
  }
}

__global__ __launch_bounds__(256)
void prep_wd(const float* __restrict__ Wd, const float* __restrict__ vBd,
             const float* __restrict__ tmBd, __bf16* __restrict__ Wda) {
  int o = blockIdx.x, t = threadIdx.x;
  const float4* w4 = (const float4*)(Wd + (size_t)o * I_DIM);
  __bf16* orow = Wda + (size_t)o * K2P;
  for (int c = t; c < I_DIM / 4; c += 256) {
    float4 v = w4[c];
    bf16x4 b = {(__bf16)v.x, (__bf16)v.y, (__bf16)v.z, (__bf16)v.w};
    *(bf16x4*)(orow + c * 4) = b;
  }
  if (t < 128) {
    float v = 0.f;
    if (t < 8) v = 2.f * vBd[o * R_RANK + t];
    else if (t < 40) { int e = (t - 8) >> 3, r = (t - 8) & 7;
      v = 2.f * tmBd[((size_t)e * H_DIM + o) * R_RANK + r]; }
    orow[I_DIM + t] = (__bf16)v;
  }
}

__global__ __launch_bounds__(256)
void prep_x(const float* __restrict__ x, const void* __restrict__ mask,
            const float* __restrict__ vAg, const float* __restrict__ tmAg, const float* __restrict__ rg,
            const float* __restrict__ vAu, const float* __restrict__ tmAu, const float* __restrict__ ru,
            __bf16* __restrict__ Xaug) {
  __shared__ __align__(16) float sx[4][H_DIM];
  __shared__ float dots[4][88];
  __shared__ int okI, okF;
  int t = threadIdx.x, n0 = blockIdx.x * 4;
  if (t == 0) { okI = 1; okF = 1; }
  __syncthreads();
  detect_mask(mask, t, &okI, &okF);
  for (int tok = 0; tok < 4; ++tok) {
    const float4* xr = (const float4*)(x + (size_t)(n0 + tok) * H_DIM);
    __bf16* orow = Xaug + (size_t)(n0 + tok) * K1P;
    for (int c = t; c < H_DIM / 4; c += 256) {
      float4 v = xr[c];
      *(float4*)&sx[tok][c * 4] = v;
      bf16x4 b = {(__bf16)v.x, (__bf16)v.y, (__bf16)v.z, (__bf16)v.w};
      *(bf16x4*)(orow + c * 4) = b;
    }
  }
  __syncthreads();
  int wv = t >> 6, ln = t & 63;
  for (int idx = wv; idx < 88; idx += 4) {
    const float* wrow;
    if      (idx <  8) wrow = vAg  + (size_t)idx * H_DIM;
    else if (idx < 40) wrow = tmAg + (size_t)(idx - 8) * H_DIM;
    else if (idx < 44) wrow = rg   + (size_t)(idx - 40) * H_DIM;
    else if (idx < 52) wrow = vAu  + (size_t)(idx - 44) * H_DIM;
    else if (idx < 84) wrow = tmAu + (size_t)(idx - 52) * H_DIM;
    else               wrow = ru   + (size_t)(idx - 84) * H_DIM;
    float a0 = 0, a1 = 0, a2 = 0, a3 = 0;
    for (int j = 0; j < H_DIM / 64; ++j) {
      int h = j * 64 + ln;
      float w = wrow[h];
      a0 = fmaf(sx[0][h], w, a0);
      a1 = fmaf(sx[1][h], w, a1);
      a2 = fmaf(sx[2][h], w, a2);
      a3 = fmaf(sx[3][h], w, a3);
    }
    for (int s = 32; s > 0; s >>= 1) {
      a0 += __shfl_xor(a0, s); a1 += __shfl_xor(a1, s);
      a2 += __shfl_xor(a2, s); a3 += __shfl_xor(a3, s);
    }
    if (ln == 0) { dots[0][idx] = a0; dots[1][idx] = a1; dots[2][idx] = a2; dots[3][idx] = a3; }
  }
  __syncthreads();
  for (int pass = 0; pass < 2; ++pass) {
    int tok = (t >> 7) + pass * 2;
    int s = t & 127;
    const float* dd = dots[tok];
    bool img = read_mask(mask, n0 + tok, okI, okF);
    float c = 0.f;
    if (s < 80) {
      if (s < 40) {
        if (img) { if (s < 8) c = dd[s]; }
        else if (s >= 8) {
          float l0 = dd[40], l1 = dd[41], l2 = dd[42], l3 = dd[43];
          float mx = fmaxf(fmaxf(l0, l1), fmaxf(l2, l3));
          float e0 = __expf(l0 - mx), e1 = __expf(l1 - mx), e2 = __expf(l2 - mx), e3 = __expf(l3 - mx);
          float inv = 1.f / (e0 + e1 + e2 + e3);
          int e = (s - 8) >> 3;
          float ge = (e == 0 ? e0 : e == 1 ? e1 : e == 2 ? e2 : e3) * inv;
          c = ge * dd[s];
        }
      } else {
        int s2 = s - 40;
        if (img) { if (s2 < 8) c = dd[44 + s2]; }
        else if (s2 >= 8) {
          float l0 = dd[84], l1 = dd[85], l2 = dd[86], l3 = dd[87];
          float mx = fmaxf(fmaxf(l0, l1), fmaxf(l2, l3));
          float e0 = __expf(l0 - mx), e1 = __expf(l1 - mx), e2 = __expf(l2 - mx), e3 = __expf(l3 - mx);
          float inv = 1.f / (e0 + e1 + e2 + e3);
          int e = (s2 - 8) >> 3;
          float ge = (e == 0 ? e0 : e == 1 ? e1 : e == 2 ? e2 : e3) * inv;
          c = ge * dd[44 + s2];
        }
      }
    }
    Xaug[(size_t)(n0 + tok) * K1P + H_DIM + s] = (__bf16)c;
  }
}

__global__ __launch_bounds__(256)
void prep_x2(const void* __restrict__ mask, const float* __restrict__ vAd,
             const float* __restrict__ tmAd, const float* __restrict__ rd,
             __bf16* __restrict__ X2) {
  __shared__ __align__(16) __bf16 si[4][I_DIM];
  __shared__ float dots[4][44];
  __shared__ int okI, okF;
  int t = threadIdx.x, n0 = blockIdx.x * 4;
  if (t == 0) { okI = 1; okF = 1; }
  __syncthreads();
  detect_mask(mask, t, &okI, &okF);
  for (int tok = 0; tok < 4; ++tok) {
    const bf16x8* xr = (const bf16x8*)(X2 + (size_t)(n0 + tok) * K2P);
    bf16x8* srow = (bf16x8*)&si[tok][0];
    for (int c = t; c < I_DIM / 8; c += 256) srow[c] = xr[c];
  }
  __syncthreads();
  int wv = t >> 6, ln = t & 63;
  for (int idx = wv; idx < 44; idx += 4) {
    const float* wrow = (idx < 8)  ? vAd  + (size_t)idx * I_DIM
                      : (idx < 40) ? tmAd + (size_t)(idx - 8) * I_DIM
                                   : rd   + (size_t)(idx - 40) * I_DIM;
    float a0 = 0, a1 = 0, a2 = 0, a3 = 0;
    for (int j = 0; j < I_DIM / 64; ++j) {
      int h = j * 64 + ln;
      float w = wrow[h];
      a0 = fmaf((float)si[0][h], w, a0);
      a1 = fmaf((float)si[1][h], w, a1);
      a2 = fmaf((float)si[2][h], w, a2);
      a3 = fmaf((float)si[3][h], w, a3);
    }
    for (int s = 32; s > 0; s >>= 1) {
      a0 += __shfl_xor(a0, s); a1 += __shfl_xor(a1, s);
      a2 += __shfl_xor(a2, s); a3 += __shfl_xor(a3, s);
    }
    if (ln == 0) { dots[0][idx] = a0; dots[1][idx] = a1; dots[2][idx] = a2; dots[3][idx] = a3; }
  }
  __syncthreads();
  for (int pass = 0; pass < 2; ++pass) {
    int tok = (t >> 7) + pass * 2;
    int s = t & 127;
    const float* dd = dots[tok];
    bool img = read_mask(mask, n0 + tok, okI, okF);
    float c = 0.f;
    if (s < 40) {
      if (img) { if (s < 8) c = dd[s]; }
      else if (s >= 8) {
        float l0 = dd[40], l1 = dd[41], l2 = dd[42], l3 = dd[43];
        float mx = fmaxf(fmaxf(l0, l1), fmaxf(l2, l3));
        float e0 = __expf(l0 - mx), e1 = __expf(l1 - mx), e2 = __expf(l2 - mx), e3 = __expf(l3 - mx);
        float inv = 1.f / (e0 + e1 + e2 + e3);
        int e = (s - 8) >> 3;
        float ge = (e == 0 ? e0 : e == 1 ? e1 : e == 2 ? e2 : e3) * inv;
        c = ge * dd[s];
      }
    }
    X2[(size_t)(n0 + tok) * K2P + I_DIM + s] = (__bf16)c;
  }
}

// ---------------------------------------------------------------------------
// 256x256 BK=64 8-wave phased GEMM, T2 swizzle, counted vmcnt, b1 read-ahead
// with counted lgkmcnt(4). EPI=0: plain fp32 store. EPI=1: silu(g)*u fusion
// (B packed [128 gate|128 up] per tile; wn>=2 exchange up-acc via LDS).
// ---------------------------------------------------------------------------
template<int MH, int NH>
__device__ __forceinline__ void mfmaq(f32x4 (&acc)[8][4], const bf16x8 (&av)[4][2],
                                      const bf16x8 (&bv)[2][2]) {
#pragma unroll
  for (int kk = 0; kk < 2; ++kk)
#pragma unroll
    for (int j = 0; j < 2; ++j)
#pragma unroll
      for (int i = 0; i < 4; ++i)
        acc[MH * 4 + i][NH * 2 + j] = __builtin_amdgcn_mfma_f32_16x16x32_bf16(
            av[i][kk], bv[j][kk], acc[MH * 4 + i][NH * 2 + j], 0, 0, 0);
}

template<int KS, int NT, int GN, typename OutT, int OSTR, int EPI>
__global__ __launch_bounds__(512, 2)
void gemm256(const __bf16* __restrict__ A, const __bf16* __restrict__ Bm,
             OutT* __restrict__ C) {
  __shared__ __align__(16) char lds[131072];

  int t = threadIdx.x;
  int w = t >> 6, l = t & 63;
  int wm = w >> 2, wn = w & 3;
  int lrow = l & 15, kq = l >> 4;

  int nwg = gridDim.x, bid = blockIdx.x;
  int swz = (bid & 7) * (nwg >> 3) + (bid >> 3);
  int tm = swz / GN, tn = swz % GN;
  int m0 = tm * 256, n0 = tn * 256;

  // staging: per-lane inverse-swizzled global source; linear LDS dest
  int grow = (t >> 3) & 7;
  int gcole = ((t & 7) ^ grow) << 3;
  const __bf16* gA0 = A  + (size_t)(m0 + w * 8 + grow) * KS + gcole;
  const __bf16* gB0 = Bm + (size_t)(n0 + w * 8 + grow) * KS + gcole;
  char* ldsA0 = lds + w * 1024;
  char* ldsB0 = lds + 32768 + w * 1024;

  auto stageA = [&](int buf, int tt, int c) {
    gload16(gA0 + (size_t)c * (64 * KS) + (size_t)tt * 64,
            ldsA0 + buf * 65536 + c * 8192);
  };
  auto stageB = [&](int buf, int tt, int c) {
    gload16(gB0 + (size_t)c * (64 * KS) + (size_t)tt * 64,
            ldsB0 + buf * 65536 + c * 8192);
  };

  // swizzled ds_read addressing
  int aBase = (wm * 128 + lrow) * 128;
  int bBase = (wn * 64 + lrow) * 128;
  int sw    = (lrow & 7) << 4;
  int col0  = (kq * 16) ^ sw;
  int col1  = (64 + kq * 16) ^ sw;

  f32x4 acc[8][4];
#pragma unroll
  for (int i = 0; i < 8; ++i)
#pragma unroll
    for (int j = 0; j < 4; ++j) acc[i][j] = (f32x4){0.f, 0.f, 0.f, 0.f};

  // prologue: tiles 0 -> buf0, 1 -> buf1
#pragma unroll
  for (int c = 0; c < 4; ++c) { stageA(0, 0, c); stageB(0, 0, c); }
#pragma unroll
  for (int c = 0; c < 4; ++c) { stageA(1, 1, c); stageB(1, 1, c); }
  asm volatile("s_waitcnt vmcnt(8)" ::: "memory");
  BAR();

  int cur = 0;
  for (int tt = 0; tt < NT; ++tt, cur ^= 1) {
    const char* sa = lds + (cur ? 65536 : 0);
    const char* sb = sa + 32768;
    int t2 = tt + 2;
    bool st = t2 < NT;
    bf16x8 aF[4][2], b0[2][2], b1[2][2];

    // P1: aLo(8) + b0(4) reads, then b1(4) as read-ahead; lgkmcnt(4); Q00
#pragma unroll
    for (int i = 0; i < 4; ++i) {
      aF[i][0] = *(const bf16x8*)(sa + aBase + i * 2048 + col0);
      aF[i][1] = *(const bf16x8*)(sa + aBase + i * 2048 + col1);
    }
#pragma unroll
    for (int j = 0; j < 2; ++j) {
      b0[j][0] = *(const bf16x8*)(sb + bBase + j * 2048 + col0);
      b0[j][1] = *(const bf16x8*)(sb + bBase + j * 2048 + col1);
    }
    __builtin_amdgcn_sched_barrier(0);   // pin: b1 reads issue AFTER aLo/b0
#pragma unroll
    for (int j = 0; j < 2; ++j) {
      b1[j][0] = *(const bf16x8*)(sb + bBase + (2 + j) * 2048 + col0);
      b1[j][1] = *(const bf16x8*)(sb + bBase + (2 + j) * 2048 + col1);
    }
    BAR(); LGKM4();
    __builtin_amdgcn_s_setprio(1);
    mfmaq<0, 0>(acc, aF, b0);
    __builtin_amdgcn_s_setprio(0);
    BAR();

    // P2: stage A[t+2] chunks 0,2 (aLo consumed); no reads; Q01 (b1 drained)
    if (st) { stageA(cur, t2, 0); stageA(cur, t2, 2); }
    BAR(); LGKM0();
    __builtin_amdgcn_s_setprio(1);
    mfmaq<0, 1>(acc, aF, b1);
    __builtin_amdgcn_s_setprio(0);
    BAR();

    // P3: stage B[t+2] chunks 0,1 ; read aHi(8); Q10
    if (st) { stageB(cur, t2, 0); stageB(cur, t2, 1); }
#pragma unroll
    for (int i = 0; i < 4; ++i) {
      aF[i][0] = *(const bf16x8*)(sa + aBase + (4 + i) * 2048 + col0);
      aF[i][1] = *(const bf16x8*)(sa + aBase + (4 + i) * 2048 + col1);
    }
    BAR(); LGKM0();
    __builtin_amdgcn_s_setprio(1);
    mfmaq<1, 0>(acc, aF, b0);
    __builtin_amdgcn_s_setprio(0);
    BAR();

    // P4: stage B[t+2] 2,3 + A[t+2] 1,3; Q11; counted vmcnt
    if (st) { stageB(cur, t2, 2); stageB(cur, t2, 3);
              stageA(cur, t2, 1); stageA(cur, t2, 3); }
    __builtin_amdgcn_s_setprio(1);
    mfmaq<1, 1>(acc, aF, b1);
    __builtin_amdgcn_s_setprio(0);
    if (st) asm volatile("s_waitcnt vmcnt(8)" ::: "memory");
    else    asm volatile("s_waitcnt vmcnt(0)" ::: "memory");
    BAR();
  }

  if constexpr (EPI == 0) {
    int r0 = m0 + wm * 128 + kq * 4;
    int c0 = n0 + wn * 64 + lrow;
#pragma unroll
    for (int mi = 0; mi < 8; ++mi) {
#pragma unroll
      for (int q = 0; q < 4; ++q) {
        OutT* p = C + (size_t)(r0 + mi * 16 + q) * OSTR + c0;
#pragma unroll
        for (int ni = 0; ni < 4; ++ni) p[ni * 16] = (OutT)acc[mi][ni][q];
      }
    }
  } else {
    // silu fusion: local cols 0..127 = gate(tn*128 + c), 128..255 = up(same c).
    // up-waves (wn>=2) publish acc via LDS; gate-waves compute silu(g)*u.
    float* xch = (float*)lds;
    if (wn >= 2) {
      float* base = xch + (size_t)(wm * 2 + (wn - 2)) * 8192;
#pragma unroll
      for (int mi = 0; mi < 8; ++mi)
#pragma unroll
        for (int q = 0; q < 4; ++q)
#pragma unroll
          for (int ni = 0; ni < 4; ++ni)
            base[(mi * 16 + kq * 4 + q) * 64 + ni * 16 + lrow] = acc[mi][ni][q];
    }
    __syncthreads();
    if (wn < 2) {
      const float* base = xch + (size_t)(wm * 2 + wn) * 8192;
#pragma unroll
      for (int mi = 0; mi < 8; ++mi) {
#pragma unroll
        for (int q = 0; q < 4; ++q) {
          int row = m0 + wm * 128 + mi * 16 + kq * 4 + q;
          OutT* orow = C + (size_t)row * OSTR + tn * 128 + wn * 64 + lrow;
#pragma unroll
          for (int ni = 0; ni < 4; ++ni) {
            float g = acc[mi][ni][q];
            float u = base[(mi * 16 + kq * 4 + q) * 64 + ni * 16 + lrow];
            orow[ni * 16] = (OutT)(g / (1.f + __expf(-g)) * u);
          }
        }
      }
    }
  }
}

// ---------------------------------------------------------------------------
extern "C" void kernel_launch(void* const* d_in, const int* in_sizes, int n_in,
                              void* d_out, int out_size, void* d_ws, size_t ws_size,
                              hipStream_t stream) {
  const float* x    = (const float*)d_in[0];
  const void*  mask = d_in[1];
  const float* Wg   = (const float*)d_in[2];
  const float* Wu   = (const float*)d_in[3];
  const float* Wd   = (const float*)d_in[4];
  const float* vAg  = (const float*)d_in[5];
  const float* vBg  = (const float*)d_in[6];
  const float* vAu  = (const float*)d_in[7];
  const float* vBu  = (const float*)d_in[8];
  const float* vAd  = (const float*)d_in[9];
  const float* vBd  = (const float*)d_in[10];
  const float* rg   = (const float*)d_in[11];
  const float* tmAg = (const float*)d_in[12];
  const float* tmBg = (const float*)d_in[13];
  const float* ru   = (const float*)d_in[14];
  const float* tmAu = (const float*)d_in[15];
  const float* tmBu = (const float*)d_in[16];
  const float* rd   = (const float*)d_in[17];
  const float* tmAd = (const float*)d_in[18];
  const float* tmBd = (const float*)d_in[19];

  // workspace layout (bytes), total 403,046,400 (== round-0's proven size):
  //   Xaug 0 .. 34,603,008
  //   Wcat 34,603,008 .. 220,594,176   (22016 x 4224 bf16, interleaved g/u)
  //   X2   220,594,176 .. 311,820,288  (4096 x 11136 bf16)
  //   Wda  311,820,288 .. 403,046,400  (4096 x 11136 bf16)
  char* ws = (char*)d_ws;
  __bf16* Xaug = (__bf16*)(ws);
  __bf16* Wcat = (__bf16*)(ws + 34603008);
  __bf16* X2   = (__bf16*)(ws + 220594176);
  __bf16* Wda  = (__bf16*)(ws + 311820288);

  prep_w1<<<I_DIM, 256, 0, stream>>>(Wg, Wu, vBg, tmBg, vBu, tmBu, Wcat);
  prep_x<<<N_TOK / 4, 256, 0, stream>>>(x, mask, vAg, tmAg, rg, vAu, tmAu, ru, Xaug);

  // GEMM1 fused: grid 16*86 = 1376 (%8==0); writes silu(g)*u into X2 cols 0..11007
  gemm256<K1P, K1P / 64, 86, __bf16, K2P, 1>
      <<<(N_TOK / 256) * 86, 512, 0, stream>>>(Xaug, Wcat, X2);

  prep_wd<<<H_DIM, 256, 0, stream>>>(Wd, vBd, tmBd, Wda);
  prep_x2<<<N_TOK / 4, 256, 0, stream>>>(mask, vAd, tmAd, rd, X2);

  // GEMM2: grid 16*16 = 256
  gemm256<K2P, K2P / 64, H_DIM / 256, float, H_DIM, 0>
      <<<(N_TOK / 256) * (H_DIM / 256), 512, 0, stream>>>(X2, Wda, (float*)d_out);
}